// Round 6
// baseline (226.741 us; speedup 1.0000x reference)
//
#include <hip/hip_runtime.h>
#include <stdint.h>

// 7x7 conv, stride 1, pad 3, on 64 x 512 x 512 fp32 (single channel).
// out[n,y,x] = sum_{ky,kx} x[n, y+ky-3, x+kx-3] * w[ky,kx]
//
// R13: NO LDS, NO BARRIER — pure streaming conv served by L1/L2.
//   - R9..R12 post-mortem: occupancy 33->46->~70%, conflicts 2.9e6->1.14e7->0,
//     b128->b64, edge-path removal: ALL flat at ~41 us. VALU ~37%, HBM ~35%,
//     LDS <30% -> nothing saturated in ANY variant. The invariant is the
//     stage->syncthreads(vmcnt drain)->compute convoy: blocks alternate load
//     bursts with silent compute, phase-locked -> memory pipe idles ~half the
//     time. No knob inside that structure moved it.
//   - Fix: remove the structure. Each thread loads its own 10 rows x 3 f4
//     (16B-aligned; a wave's load = contiguous 1 KB span; the 3 spans/row
//     overlap -> L1-hit; y-halo across waves/blocks -> L2/L3-hit). Loads
//     issue continuously from every wave; no barriers anywhere.
//   - y-guard is wave-uniform (wave = 4-row strip, lanes span x). x-guard
//     masks only lane 0 / lane 63 at the image borders (exec-masked loads).
//   - FMA block copied verbatim from passing R10/R12 -> identical numerics.

#define IMG_W 512
#define IMG_H 512
#define NIMG  64
#define TW    256            // output cols per block (64 lanes x 4)
#define TH    16             // output rows per block (4 waves x 4)

__global__ __launch_bounds__(256, 4) void conv7x7_kernel(
    const float* __restrict__ x,
    const float* __restrict__ wgt,
    float* __restrict__ out)
{
    const int tid  = threadIdx.x;
    const int wave = tid >> 6;
    const int lane = tid & 63;
    const int bx   = blockIdx.x * TW;
    const int by   = blockIdx.y * TH;
    const int n    = blockIdx.z;

    const float* img = x + (size_t)n * (IMG_W * IMG_H);
    float* o = out + (size_t)n * (IMG_W * IMG_H);

    // ---- weights: wave-uniform -> SGPRs ----
    float w[49];
    #pragma unroll
    for (int i = 0; i < 49; ++i) w[i] = wgt[i];

    const int lx = bx + lane * 4;    // global x of this thread's first output
    const int ry = by + wave * 4;    // global y of this thread's first output

    // x-border masks: only lane 0 at bx==0 / lane 63 at right edge are OOB.
    const bool has_left  = (lx != 0);
    const bool has_right = (lx != IMG_W - 4);

    float acc[4][4] = {};

    #pragma unroll
    for (int r = 0; r < 10; ++r) {
        const int gy = ry - 3 + r;            // wave-uniform
        float4 a = make_float4(0.f, 0.f, 0.f, 0.f);
        float4 b = a, c = a;
        if ((unsigned)gy < IMG_H) {           // wave-uniform branch
            const float* rp = img + (size_t)gy * IMG_W + lx;
            if (has_left)  a = *(const float4*)(rp - 4);   // cols lx-4..lx-1
            b = *(const float4*)rp;                        // cols lx  ..lx+3
            if (has_right) c = *(const float4*)(rp + 4);   // cols lx+4..lx+7
        }
        const float row[12] = {a.x, a.y, a.z, a.w,
                               b.x, b.y, b.z, b.w,
                               c.x, c.y, c.z, c.w};
        #pragma unroll
        for (int j = 0; j < 4; ++j) {
            const int ky = r - j;
            if (ky >= 0 && ky < 7) {
                #pragma unroll
                for (int kx = 0; kx < 7; ++kx) {
                    const float wv = w[ky * 7 + kx];
                    #pragma unroll
                    for (int cc = 0; cc < 4; ++cc)
                        acc[j][cc] = fmaf(row[1 + kx + cc], wv, acc[j][cc]);
                }
            }
        }
    }

    // ---- store: 4 rows of float4 per thread (contiguous per wave) ----
    #pragma unroll
    for (int j = 0; j < 4; ++j) {
        float4 v = make_float4(acc[j][0], acc[j][1], acc[j][2], acc[j][3]);
        *(float4*)&o[(size_t)(ry + j) * IMG_W + lx] = v;
    }
}

extern "C" void kernel_launch(void* const* d_in, const int* in_sizes, int n_in,
                              void* d_out, int out_size, void* d_ws, size_t ws_size,
                              hipStream_t stream)
{
    const float* x   = (const float*)d_in[0];
    const float* wgt = (const float*)d_in[1];
    float* out       = (float*)d_out;

    // 2 x 32 x 64 = 4096 blocks of 256 threads
    dim3 grid(IMG_W / TW, IMG_H / TH, NIMG);
    conv7x7_kernel<<<grid, 256, 0, stream>>>(x, wgt, out);
}

// Round 7
// 118.019 us; speedup vs baseline: 1.9212x; 1.9212x over previous
//
#include <hip/hip_runtime.h>
#include <stdint.h>

// 7x7 conv, stride 1, pad 3, on 64 x 512 x 512 fp32 (single channel).
// out[n,y,x] = sum_{ky,kx} x[n, y+ky-3, x+kx-3] * w[ky,kx]
//
// R14: R10 (best: ~34.6us conv) + 2-deep REGISTER ROW PIPELINE.
//   - R13 post-mortem: no-LDS streaming -> 480 MB DRAM traffic (L2 blown by
//     concurrent working set) -> 146us. LDS staging is what keeps HBM at the
//     ~118 MB minimum. Reverted.
//   - R10's VGPR_Count=40 == exactly q[6]+acc[16]+addr: the compiler did ZERO
//     row-ahead prefetch. Each row: issue 6 ds_read_b64, stall ~120cy lgkm,
//     then ~156cy FMA -> <=56% VALU duty in compute, 37% overall.
//   - Fix (Guideline 7, ILP): fully-unrolled row loop; row r+1's 6 laundered
//     b64 loads issue BEFORE row r's FMA block into q[(r+1)&1] (parity is
//     compile-time after unroll). LDS latency hides under FMAs.
//   - Staging / barrier / b64 widths / FMA order / store identical to R10.

#define IMG_W 512
#define IMG_H 512
#define NIMG  64
#define TW    256            // output tile width per block
#define TH    16             // output tile height per block
#define HALO  3
#define LDS_W 264            // floats per row: tile col c <-> global x = bx-4+c
#define LDS_H (TH + 2*HALO)  // 22 rows

// async 16B global -> LDS (dest must be uniform base + lane*16, FULL exec)
__device__ __forceinline__ void gload_lds16(const float* src, float* dst_lds)
{
    __builtin_amdgcn_global_load_lds(
        (__attribute__((address_space(1))) void*)(uintptr_t)src,
        (__attribute__((address_space(3))) void*)(uintptr_t)dst_lds,
        16, 0, 0);
}

__global__ __launch_bounds__(256, 6) void conv7x7_kernel(
    const float* __restrict__ x,
    const float* __restrict__ wgt,
    float* __restrict__ out)
{
    __shared__ float tile[LDS_H * LDS_W];   // 23,232 B, linear

    const int tid  = threadIdx.x;
    const int wave = tid >> 6;
    const int lane = tid & 63;
    const int bx   = blockIdx.x * TW;
    const int by   = blockIdx.y * TH;
    const int n    = blockIdx.z;

    const float* img = x + (size_t)n * (IMG_W * IMG_H);

    // ---- weights: wave-uniform -> SGPRs (s_loads overlap staging) ----
    float w[49];
    #pragma unroll
    for (int i = 0; i < 49; ++i) w[i] = wgt[i];

    // ---- stage interior: per row, one full wave, c4=1..64 (cols 4..259) ----
    // gx = bx + 4*lane in [bx, bx+255]: always in-bounds in x.
    // gy guard is wave-uniform -> exec stays full for every global_load_lds.
    for (int r = wave; r < LDS_H; r += 4) {
        const int gy = by - HALO + r;
        float* dst = &tile[r * LDS_W + 4 + 4 * lane];
        if ((unsigned)gy < IMG_H) {
            gload_lds16(&img[(size_t)gy * IMG_W + bx + 4 * lane], dst);
        } else {
            *(float4*)dst = make_float4(0.f, 0.f, 0.f, 0.f);  // contiguous write
        }
    }

    // ---- stage edges: 2 halo f4 per row (cols 0..3 and 260..263) ----
    if (tid < 2 * LDS_H) {
        const int r    = tid >> 1;
        const int side = tid & 1;
        const int cb   = side ? (LDS_W - 4) : 0;   // float col base in tile
        const int gx   = side ? (bx + 256) : (bx - 4);
        const int gy   = by - HALO + r;
        float4 v = make_float4(0.f, 0.f, 0.f, 0.f);
        if (((unsigned)gy < IMG_H) && ((unsigned)gx < IMG_W))
            v = *(const float4*)&img[(size_t)gy * IMG_W + gx];
        *(float4*)&tile[r * LDS_W + cb] = v;
    }

    __syncthreads();   // drains vmcnt (global_load_lds) + lgkmcnt

    // ---- compute: 4x x 4y outputs per thread, 6 ds_read_b64 per row,
    //      2-deep row pipeline in registers ----
    const int lx = lane * 4;        // output x within tile
    const int rbase = wave * 4;

    // Laundered 8-byte deltas: opaque to the vectorizer -> loads stay as
    // individual ds_read_b64 (the conflict-free width), not re-merged b128.
    int d[6];
    #pragma unroll
    for (int t = 0; t < 6; ++t) {
        d[t] = t * 8;
        asm volatile("" : "+v"(d[t]));
    }

    const char* tb = (const char*)tile + (size_t)(rbase * LDS_W + lx) * 4;

    float acc[4][4] = {};
    float2 q[2][6];

    // prologue: load row 0 into q[0]
    #pragma unroll
    for (int u = 0; u < 6; ++u)
        q[0][u] = *(const float2*)(tb + d[u]);

    #pragma unroll
    for (int r = 0; r < 10; ++r) {
        // prefetch row r+1 into the alternate buffer (indices static
        // after full unroll) BEFORE consuming row r
        if (r < 9) {
            const char* rowb = tb + (size_t)(r + 1) * (LDS_W * 4);
            #pragma unroll
            for (int u = 0; u < 6; ++u)
                q[(r + 1) & 1][u] = *(const float2*)(rowb + d[u]);
        }

        const float2* qc = q[r & 1];
        const float row[12] = {qc[0].x, qc[0].y, qc[1].x, qc[1].y,
                               qc[2].x, qc[2].y, qc[3].x, qc[3].y,
                               qc[4].x, qc[4].y, qc[5].x, qc[5].y};
        #pragma unroll
        for (int j = 0; j < 4; ++j) {
            const int ky = r - j;
            if (ky >= 0 && ky < 7) {
                #pragma unroll
                for (int kx = 0; kx < 7; ++kx) {
                    const float wv = w[ky * 7 + kx];
                    #pragma unroll
                    for (int cc = 0; cc < 4; ++cc)
                        acc[j][cc] = fmaf(row[1 + kx + cc], wv, acc[j][cc]);
                }
            }
        }
    }

    // ---- store: 4 rows of float4 per thread (contiguous per wave) ----
    float* o = out + (size_t)n * (IMG_W * IMG_H);
    #pragma unroll
    for (int j = 0; j < 4; ++j) {
        float4 v = make_float4(acc[j][0], acc[j][1], acc[j][2], acc[j][3]);
        *(float4*)&o[(size_t)(by + rbase + j) * IMG_W + bx + lx] = v;
    }
}

extern "C" void kernel_launch(void* const* d_in, const int* in_sizes, int n_in,
                              void* d_out, int out_size, void* d_ws, size_t ws_size,
                              hipStream_t stream)
{
    const float* x   = (const float*)d_in[0];
    const float* wgt = (const float*)d_in[1];
    float* out       = (float*)d_out;

    dim3 grid(IMG_W / TW, IMG_H / TH, NIMG);   // 2 x 32 x 64 = 4096 blocks
    conv7x7_kernel<<<grid, 256, 0, stream>>>(x, wgt, out);
}